// Round 2
// baseline (377.709 us; speedup 1.0000x reference)
//
#include <hip/hip_runtime.h>
#include <math.h>

// B=8, N=256, D=128. score[b,i,j] = <val_i,val_j> + <dep_ij, dep_ji> is
// SYMMETRIC in (i,j) -> upper-triangle tiles only; each 512B dep row fetched
// once. R2: 8x8 (i,j) tiles; transposed side staged via LDS so ALL dep reads
// are contiguous 4-KB chunks (R1's 128KB-strided dji reads ran ~2 TB/s).

#define BB 8
#define NN 256
#define DD 128
#define T  8                    // tile edge
#define NT (NN / T)             // 32 tile rows
#define TP_PER_B ((NT * (NT + 1)) / 2)   // 528 tile-pairs per batch
#define RH (NT / 2)             // 16
#define RW (NT + 1)             // 33

constexpr float EPS = 1e-10f;
constexpr float INV_SQRT_D = 0.08838834764831845f; // 1/sqrt(128)

__global__ __launch_bounds__(256) void score_kernel(
    const float* __restrict__ val,   // [B,N,D]
    const float* __restrict__ dep,   // [B,N,N,D]
    const float* __restrict__ adj,   // [B,N,N]
    float* __restrict__ out)         // [B,N,N] <- exp(score)*adj (unnormalized)
{
    __shared__ float S[T][T][DD];    // S[j'][i'][d] = dep[b, J0+j', I0+i', d]  (32 KB)

    const int blk = blockIdx.x;
    const int b   = blk / TP_PER_B;
    const int tp  = blk - b * TP_PER_B;
    const int r   = tp / RW;
    const int c   = tp - r * RW;
    int ti, tj;                      // triangle<->rectangle: row r pairs with NT-1-r
    if (c < NT - r) { ti = r;          tj = r + c; }
    else            { ti = NT - 1 - r; tj = c - 1; }
    const int I0 = ti * T, J0 = tj * T;

    // ---- stage transposed tile: 8 iters, each one contiguous 4-KB chunk ----
    {
        const int tid = threadIdx.x;
        #pragma unroll
        for (int k = 0; k < 8; ++k) {
            const int idx = k * 256 + tid;     // float4 index in [0, 2048)
            const int jj  = idx >> 8;          // == k
            const int ii  = (idx >> 5) & 7;
            const int l   = idx & 31;
            const float4* src = (const float4*)(dep
                + (((size_t)b * NN + (J0 + jj)) * NN + (I0 + ii)) * DD) + l;
            ((float4*)S)[idx] = *src;          // layout-identical linear store
        }
    }
    __syncthreads();

    // ---- compute: 8 half-waves x 8 iters = 64 pairs ----
    const int hw   = threadIdx.x >> 5;   // j' within tile
    const int lane = threadIdx.x & 31;

    #pragma unroll
    for (int it = 0; it < 8; ++it) {
        const int i = I0 + it;
        const int j = J0 + hw;

        const float4 a = ((const float4*)(dep + (((size_t)b * NN + i) * NN + j) * DD))[lane];
        const float4 t = ((const float4*)&S[hw][it][0])[lane];
        const float4 x = ((const float4*)(val + ((size_t)b * NN + i) * DD))[lane];
        const float4 y = ((const float4*)(val + ((size_t)b * NN + j) * DD))[lane];

        float p = a.x * t.x + a.y * t.y + a.z * t.z + a.w * t.w
                + x.x * y.x + x.y * y.y + x.z * y.z + x.w * y.w;

        #pragma unroll
        for (int m = 16; m >= 1; m >>= 1) p += __shfl_xor(p, m, 64);

        if (lane == 0) {
            const float e = __expf(p * INV_SQRT_D);
            const size_t base = (size_t)b * NN * NN;
            const size_t ij = base + (size_t)i * NN + j;
            const size_t ji = base + (size_t)j * NN + i;
            out[ij] = e * adj[ij];
            out[ji] = e * adj[ji];   // diag tiles: duplicate same-value store, benign
        }
    }
}

__global__ __launch_bounds__(256) void norm_kernel(float* __restrict__ out)
{
    const int row = blockIdx.x;              // b*N + i
    const int tid = threadIdx.x;             // j
    const size_t idx = (size_t)row * NN + tid;
    const float x = out[idx];

    float s = x;
    #pragma unroll
    for (int m = 32; m >= 1; m >>= 1) s += __shfl_xor(s, m, 64);

    __shared__ float ws[4];
    __shared__ float denom_s;
    const int wid = tid >> 6;
    if ((tid & 63) == 0) ws[wid] = s;
    __syncthreads();
    if (tid == 0) denom_s = ws[0] + ws[1] + ws[2] + ws[3] + EPS;
    __syncthreads();

    out[idx] = x / denom_s;
}

extern "C" void kernel_launch(void* const* d_in, const int* in_sizes, int n_in,
                              void* d_out, int out_size, void* d_ws, size_t ws_size,
                              hipStream_t stream) {
    const float* val = (const float*)d_in[0];
    const float* dep = (const float*)d_in[1];
    const float* adj = (const float*)d_in[2];
    float* out = (float*)d_out;

    score_kernel<<<BB * TP_PER_B, 256, 0, stream>>>(val, dep, adj, out);
    norm_kernel<<<BB * NN, 256, 0, stream>>>(out);
}

// Round 3
// 318.948 us; speedup vs baseline: 1.1842x; 1.1842x over previous
//
#include <hip/hip_runtime.h>
#include <math.h>

// B=8, N=256, D=128. score[b,i,j] = <val_i,val_j> + <dep_ij, dep_ji> is
// SYMMETRIC in (i,j) -> one half-wave per unordered pair.
// R3 key insight: out[b,i,j] = exp(score)*adj[b,i,j] and adj is ~5% dense
// (plus diagonal). If adj[ij]==0 AND adj[ji]==0 (exact 0.0f inputs), the
// score is never needed -> write exact zeros and SKIP the dep row reads.
// dep traffic drops 256 MB -> ~27 MB (only ~10% of pairs need the gather).

#define BB 8
#define NN 256
#define DD 128

constexpr float EPS = 1e-10f;
constexpr float INV_SQRT_D = 0.08838834764831845f; // 1/sqrt(128)

constexpr int RECT_H = NN / 2;            // 128
constexpr int RECT_W = NN + 1;            // 257
constexpr int PAIRS_PER_BATCH = RECT_H * RECT_W;   // 32896 = N(N+1)/2
constexpr int TOTAL_PAIRS = BB * PAIRS_PER_BATCH;  // 263168
constexpr int PAIRS_PER_ITER  = 8;                 // 256 threads / 32 lanes
constexpr int ITERS_PER_BLOCK = 4;
constexpr int PAIRS_PER_BLOCK = PAIRS_PER_ITER * ITERS_PER_BLOCK;  // 32

__global__ __launch_bounds__(256) void score_kernel(
    const float* __restrict__ val,   // [B,N,D]
    const float* __restrict__ dep,   // [B,N,N,D]
    const float* __restrict__ adj,   // [B,N,N]
    float* __restrict__ out)         // [B,N,N] <- exp(score)*adj (unnormalized)
{
    const int hw   = threadIdx.x >> 5;
    const int lane = threadIdx.x & 31;

    #pragma unroll
    for (int it = 0; it < ITERS_PER_BLOCK; ++it) {
        const int pair = (blockIdx.x * ITERS_PER_BLOCK + it) * PAIRS_PER_ITER + hw;

        const int b = pair / PAIRS_PER_BATCH;
        const int t = pair - b * PAIRS_PER_BATCH;
        const int r = t / RECT_W;
        const int c = t - r * RECT_W;
        // triangle<->rectangle: row r pairs with row N-1-r
        int i, j;
        if (c < NN - r) { i = r;          j = r + c; }
        else            { i = NN - 1 - r; j = c - 1; }

        const size_t base = (size_t)b * NN * NN;
        const size_t ij = base + (size_t)i * NN + j;
        const size_t ji = base + (size_t)j * NN + i;

        // broadcast loads (uniform address within the half-wave)
        const float aij = adj[ij];
        const float aji = adj[ji];

        if (aij != 0.0f || aji != 0.0f) {
            const float4 a = ((const float4*)(dep + (ij) * DD))[lane];
            const float4 bt = ((const float4*)(dep + (ji) * DD))[lane];
            const float4 x = ((const float4*)(val + ((size_t)b * NN + i) * DD))[lane];
            const float4 y = ((const float4*)(val + ((size_t)b * NN + j) * DD))[lane];

            float p = a.x * bt.x + a.y * bt.y + a.z * bt.z + a.w * bt.w
                    + x.x * y.x  + x.y * y.y  + x.z * y.z  + x.w * y.w;

            #pragma unroll
            for (int m = 16; m >= 1; m >>= 1) p += __shfl_xor(p, m, 64);

            if (lane == 0) {
                const float e = __expf(p * INV_SQRT_D);
                out[ij] = e * aij;
                out[ji] = e * aji;   // i==j: same addr, same value, same thread
            }
        } else {
            // adj zero both directions (i!=j here: diag always has adj==1)
            if (lane == 0) {
                out[ij] = 0.0f;
                out[ji] = 0.0f;
            }
        }
    }
}

__global__ __launch_bounds__(256) void norm_kernel(float* __restrict__ out)
{
    const int row = blockIdx.x;              // b*N + i
    const int tid = threadIdx.x;             // j
    const size_t idx = (size_t)row * NN + tid;
    const float x = out[idx];

    float s = x;
    #pragma unroll
    for (int m = 32; m >= 1; m >>= 1) s += __shfl_xor(s, m, 64);

    __shared__ float ws[4];
    __shared__ float denom_s;
    const int wid = tid >> 6;
    if ((tid & 63) == 0) ws[wid] = s;
    __syncthreads();
    if (tid == 0) denom_s = ws[0] + ws[1] + ws[2] + ws[3] + EPS;
    __syncthreads();

    out[idx] = x / denom_s;
}

extern "C" void kernel_launch(void* const* d_in, const int* in_sizes, int n_in,
                              void* d_out, int out_size, void* d_ws, size_t ws_size,
                              hipStream_t stream) {
    const float* val = (const float*)d_in[0];
    const float* dep = (const float*)d_in[1];
    const float* adj = (const float*)d_in[2];
    float* out = (float*)d_out;

    static_assert(TOTAL_PAIRS % PAIRS_PER_BLOCK == 0, "grid exact");
    score_kernel<<<TOTAL_PAIRS / PAIRS_PER_BLOCK, 256, 0, stream>>>(val, dep, adj, out);
    norm_kernel<<<BB * NN, 256, 0, stream>>>(out);
}